// Round 5
// baseline (274.319 us; speedup 1.0000x reference)
//
#include <hip/hip_runtime.h>
#include <math.h>

// GaussianAdjacencyMatrix: out[b,i,j] = m*exp(-||x_i-x_j||^2/sigma^2) / (row_sum + 1e-8)
// B=8, N=2048, D=3.
//
// v5: persistent blocks, barrier-free steady state.
//  - Grid = rows/16 = 1024 blocks = 256 CU x 4 resident (32 waves/CU, 100% occ,
//    VGPR capped <=64 by __launch_bounds__(512,8); LDS 32 KiB -> 4 blocks/CU).
//    One block owns 16 consecutive rows of one batch -> NO dispatch churn,
//    q-plane staging + sigma prologue amortized over 16 rows.
//  - Softmax invariance: drop row-constant exp(-||xi||^2/s^2);
//    A'[i,j] = exp2( xi*qx[j] + yi*qy[j] + zi*qz[j] + qw[j] ),
//    q[j] = { 2x C, 2y C, 2z C, -||x||^2 C }, C = log2(e)/sigma^2.
//  - ONE WAVE PER ROW: row sum is a 6-step shfl_xor butterfly -> zero
//    __syncthreads after staging (no vmcnt(0) drain in the steady path).
//  - Masks are the only vmem loads (q-planes on the lgkm queue): the compiler
//    emits counted vmcnt per chunk, pipelining exp compute under load return.
//  - Nontemporal stores: out has zero reuse; keep L3 for the mask stream.

#define NN      2048
#define THREADS 512
#define ROWS_PER_BLOCK 16
#define EPS     1e-8f

typedef float vf4 __attribute__((ext_vector_type(4)));

__global__ __launch_bounds__(THREADS, 8) void gauss_adj_kernel(
    const float* __restrict__ coords,   // [B, N, 3]
    const float* __restrict__ masks,    // [B, N, N]
    const float* __restrict__ sigma,    // [1]
    float* __restrict__ out)            // [B, N, N]
{
    const int tid  = threadIdx.x;
    const int wid  = tid >> 6;
    const int lane = tid & 63;
    const int base = blockIdx.x * ROWS_PER_BLOCK;   // 16 consecutive rows, same batch
    const int b    = base >> 11;

    __shared__ __align__(16) float qx[NN];
    __shared__ __align__(16) float qy[NN];
    __shared__ __align__(16) float qz[NN];
    __shared__ __align__(16) float qw[NN];

    const float s = sigma[0];
    const float C = 1.44269504088896341f / (s * s);   // log2(e)/sigma^2
    const float twoC = 2.0f * C;
    const float* cb = coords + (size_t)b * NN * 3;

    for (int idx = tid; idx < NN; idx += THREADS) {
        const float x = cb[idx * 3 + 0];
        const float y = cb[idx * 3 + 1];
        const float z = cb[idx * 3 + 2];
        qx[idx] = twoC * x;
        qy[idx] = twoC * y;
        qz[idx] = twoC * z;
        qw[idx] = -C * (x * x + y * y + z * z);
    }
    __syncthreads();   // the ONLY barrier in the kernel

    const vf4* qx4 = (const vf4*)qx;
    const vf4* qy4 = (const vf4*)qy;
    const vf4* qz4 = (const vf4*)qz;
    const vf4* qw4 = (const vf4*)qw;

    #pragma unroll
    for (int g = 0; g < 2; ++g) {
        const int row = base + (g << 3) + wid;   // this wave's row
        const int i   = row & (NN - 1);

        const float xi = cb[i * 3 + 0];          // L1-hot after staging
        const float yi = cb[i * 3 + 1];
        const float zi = cb[i * 3 + 2];

        const vf4* mrow = (const vf4*)(masks + (size_t)row * NN);
        vf4*       orow = (vf4*)(out + (size_t)row * NN);

        vf4 a[8];
        // issue all 8 mask loads up front (only vmcnt traffic -> counted waits)
        #pragma unroll
        for (int w = 0; w < 8; ++w) a[w] = mrow[w * 64 + lane];

        float lsum = 0.0f;
        #pragma unroll
        for (int w = 0; w < 8; ++w) {
            const int q_ = w * 64 + lane;
            const vf4 X = qx4[q_], Y = qy4[q_], Z = qz4[q_], W = qw4[q_];
            vf4 v = a[w];
            v.x *= exp2f(fmaf(xi, X.x, fmaf(yi, Y.x, fmaf(zi, Z.x, W.x))));
            v.y *= exp2f(fmaf(xi, X.y, fmaf(yi, Y.y, fmaf(zi, Z.y, W.y))));
            v.z *= exp2f(fmaf(xi, X.z, fmaf(yi, Y.z, fmaf(zi, Z.z, W.z))));
            v.w *= exp2f(fmaf(xi, X.w, fmaf(yi, Y.w, fmaf(zi, Z.w, W.w))));
            a[w] = v;
            lsum += (v.x + v.y) + (v.z + v.w);
        }

        // full-wave butterfly: every lane ends with the row total (no barrier)
        #pragma unroll
        for (int off = 32; off > 0; off >>= 1)
            lsum += __shfl_xor(lsum, off, 64);
        const float inv = 1.0f / (lsum + EPS);

        #pragma unroll
        for (int w = 0; w < 8; ++w) {
            vf4 o = a[w];
            o.x *= inv; o.y *= inv; o.z *= inv; o.w *= inv;
            __builtin_nontemporal_store(o, &orow[w * 64 + lane]);
        }
    }
}

extern "C" void kernel_launch(void* const* d_in, const int* in_sizes, int n_in,
                              void* d_out, int out_size, void* d_ws, size_t ws_size,
                              hipStream_t stream) {
    const float* coords = (const float*)d_in[0];   // [B,N,3]
    const float* masks  = (const float*)d_in[1];   // [B,N,N]
    const float* sigma  = (const float*)d_in[2];   // [1]
    float* out = (float*)d_out;

    const int B    = in_sizes[0] / (NN * 3);
    const int rows = B * NN;
    gauss_adj_kernel<<<rows / ROWS_PER_BLOCK, THREADS, 0, stream>>>(coords, masks, sigma, out);
}

// Round 6
// 243.803 us; speedup vs baseline: 1.1252x; 1.1252x over previous
//
#include <hip/hip_runtime.h>
#include <math.h>

// GaussianAdjacencyMatrix: out[b,i,j] = m*exp(-||x_i-x_j||^2/sigma^2) / (row_sum + 1e-8)
// B=8, N=2048, D=3.
//
// v6: A/B two-row software pipeline, one wave per row-slot.
//  - Diagnosis history: R0/R2/R4 (three structures) all ~80 us at ~2.5-3.3 TB/s,
//    half the 6.3 TB/s copy ceiling. Shared flaw: within a wave, the row-sum
//    dependency serializes [loads][compute][reduce][stores]; read and write
//    streams alternate instead of overlapping (a copy overlaps them and gets 2x).
//  - Fix: each wave owns TWO rows. Issue all 16 mask loads (rows A+B) up front;
//    compute+store A while B's loads are in flight; B's compute waits only on
//    its own (older) loads, so it never stalls on A's stores (in-order vmcnt:
//    waiting for B's loads permits A's 8 stores to remain outstanding).
//  - Softmax invariance: drop row-constant exp(-||xi||^2/s^2):
//    A'[i,j] = exp2( xi*qx[j] + yi*qy[j] + zi*qz[j] + qw[j] ),
//    q[j] = { 2x C, 2y C, 2z C, -||x||^2 C }, C = log2(e)/sigma^2.
//    q planes in LDS (32 KiB) keep coord reads on the lgkm queue, so masks are
//    the ONLY vmcnt traffic (no L1-behind-HBM retirement stalls).
//  - 256-thr blocks, 8 rows/block, grid=2048: constant block churn decorrelates
//    wave phases chip-wide. __launch_bounds__(256,4) caps VGPR at 128
//    (est. ~100 live) -> 16 waves/CU -> ~128 KB reads in flight per CU.
//  - One wave per row: reduce is a 6-step shfl_xor butterfly, no barriers after
//    staging. Nontemporal stores (out has zero reuse).

#define NN      2048
#define THREADS 256
#define ROWS_PER_BLOCK 8          // 4 waves x 2 rows
#define EPS     1e-8f

typedef float vf4 __attribute__((ext_vector_type(4)));

__global__ __launch_bounds__(THREADS, 4) void gauss_adj_kernel(
    const float* __restrict__ coords,   // [B, N, 3]
    const float* __restrict__ masks,    // [B, N, N]
    const float* __restrict__ sigma,    // [1]
    float* __restrict__ out)            // [B, N, N]
{
    const int tid  = threadIdx.x;
    const int wid  = tid >> 6;
    const int lane = tid & 63;
    const int base = blockIdx.x * ROWS_PER_BLOCK;   // 8 consecutive rows, same batch
    const int b    = base >> 11;

    __shared__ __align__(16) float qx[NN];
    __shared__ __align__(16) float qy[NN];
    __shared__ __align__(16) float qz[NN];
    __shared__ __align__(16) float qw[NN];

    const float s = sigma[0];
    const float C = 1.44269504088896341f / (s * s);   // log2(e)/sigma^2
    const float twoC = 2.0f * C;
    const float* cb = coords + (size_t)b * NN * 3;

    for (int idx = tid; idx < NN; idx += THREADS) {
        const float x = cb[idx * 3 + 0];
        const float y = cb[idx * 3 + 1];
        const float z = cb[idx * 3 + 2];
        qx[idx] = twoC * x;
        qy[idx] = twoC * y;
        qz[idx] = twoC * z;
        qw[idx] = -C * (x * x + y * y + z * z);
    }
    __syncthreads();   // the only barrier

    const vf4* qx4 = (const vf4*)qx;
    const vf4* qy4 = (const vf4*)qy;
    const vf4* qz4 = (const vf4*)qz;
    const vf4* qw4 = (const vf4*)qw;

    const int rA = base + wid * 2 + 0;
    const int rB = base + wid * 2 + 1;

    const vf4* mA = (const vf4*)(masks + (size_t)rA * NN);
    const vf4* mB = (const vf4*)(masks + (size_t)rB * NN);

    vf4 va[8], vb[8];

    // all 16 HBM loads (both rows) in flight before any compute
    #pragma unroll
    for (int w = 0; w < 8; ++w) va[w] = mA[w * 64 + lane];
    #pragma unroll
    for (int w = 0; w < 8; ++w) vb[w] = mB[w * 64 + lane];

#define PROC(BUF, ROW) { \
    const int i_ = (ROW) & (NN - 1); \
    const float xi = cb[i_ * 3 + 0]; \
    const float yi = cb[i_ * 3 + 1]; \
    const float zi = cb[i_ * 3 + 2]; \
    float lsum = 0.0f; \
    _Pragma("unroll") \
    for (int w = 0; w < 8; ++w) { \
        const int q_ = w * 64 + lane; \
        const vf4 X = qx4[q_], Y = qy4[q_], Z = qz4[q_], W = qw4[q_]; \
        vf4 v = BUF[w]; \
        v.x *= exp2f(fmaf(xi, X.x, fmaf(yi, Y.x, fmaf(zi, Z.x, W.x)))); \
        v.y *= exp2f(fmaf(xi, X.y, fmaf(yi, Y.y, fmaf(zi, Z.y, W.y)))); \
        v.z *= exp2f(fmaf(xi, X.z, fmaf(yi, Y.z, fmaf(zi, Z.z, W.z)))); \
        v.w *= exp2f(fmaf(xi, X.w, fmaf(yi, Y.w, fmaf(zi, Z.w, W.w)))); \
        BUF[w] = v; \
        lsum += (v.x + v.y) + (v.z + v.w); \
    } \
    _Pragma("unroll") \
    for (int off = 32; off > 0; off >>= 1) \
        lsum += __shfl_xor(lsum, off, 64); \
    const float inv_ = 1.0f / (lsum + EPS); \
    vf4* orow_ = (vf4*)(out + (size_t)(ROW) * NN); \
    _Pragma("unroll") \
    for (int w = 0; w < 8; ++w) { \
        vf4 o = BUF[w]; \
        o.x *= inv_; o.y *= inv_; o.z *= inv_; o.w *= inv_; \
        __builtin_nontemporal_store(o, &orow_[w * 64 + lane]); \
    } }

    // row A computes while row B's loads fly; B never waits on A's stores
    PROC(va, rA)
    PROC(vb, rB)
#undef PROC
}

extern "C" void kernel_launch(void* const* d_in, const int* in_sizes, int n_in,
                              void* d_out, int out_size, void* d_ws, size_t ws_size,
                              hipStream_t stream) {
    const float* coords = (const float*)d_in[0];   // [B,N,3]
    const float* masks  = (const float*)d_in[1];   // [B,N,N]
    const float* sigma  = (const float*)d_in[2];   // [1]
    float* out = (float*)d_out;

    const int B    = in_sizes[0] / (NN * 3);
    const int rows = B * NN;
    gauss_adj_kernel<<<rows / ROWS_PER_BLOCK, THREADS, 0, stream>>>(coords, masks, sigma, out);
}